// Round 8
// baseline (80.819 us; speedup 1.0000x reference)
//
#include <hip/hip_runtime.h>
#include <math.h>

#define MAXP 32

template <int CTRL>
__device__ __forceinline__ float dppadd(float v) {
    int t = __builtin_amdgcn_update_dpp(0, __float_as_int(v), CTRL, 0xF, 0xF, false);
    return v + __int_as_float(t);
}
// sum within each 16-lane group (verified on HW in R6)
__device__ __forceinline__ float sum16(float v) {
    v = dppadd<0xB1>(v);    // quad_perm(1,0,3,2)  == xor1
    v = dppadd<0x4E>(v);    // quad_perm(2,3,0,1)  == xor2
    v = dppadd<0x141>(v);   // row_half_mirror     == xor4
    v = dppadd<0x140>(v);   // row_mirror          == xor8
    return v;
}
__device__ __forceinline__ float rdlanef(float v, int l) {
    return __int_as_float(__builtin_amdgcn_readlane(__float_as_int(v), l));
}

// one point, broadcast via readlane->SGPR; padding substitutes point-0 data
// ((P)<np uniform -> s_cmp + s_cselect on SALU pipe, co-issues with VALU)
#define POINT(q, LB, P, mm) do {                                          \
    int xi = __builtin_amdgcn_readlane(__float_as_int((q).x), (LB)+(P));  \
    int yi = __builtin_amdgcn_readlane(__float_as_int((q).y), (LB)+(P));  \
    int zi = __builtin_amdgcn_readlane(__float_as_int((q).z), (LB)+(P));  \
    int wi = __builtin_amdgcn_readlane(__float_as_int((q).w), (LB)+(P));  \
    xi = ((P) < np) ? xi : x0i;                                           \
    yi = ((P) < np) ? yi : y0i;                                           \
    zi = ((P) < np) ? zi : z0i;                                           \
    wi = ((P) < np) ? wi : w0i;                                           \
    float v_ = fmaf(__int_as_float(xi), A, E2);                           \
    v_ = fmaf(__int_as_float(yi), B, v_);                                 \
    v_ = fmaf(__int_as_float(zi), C, v_);                                 \
    v_ = fmaf(__int_as_float(wi), Dk, v_);                                \
    mm = fmaxf(mm, v_);                                                   \
} while (0)

__global__ __launch_bounds__(256, 8) void pfn_kernel(
    const float* __restrict__ voxels,
    const int*   __restrict__ num_points,
    const int*   __restrict__ coords,
    const float* __restrict__ W,
    const float* __restrict__ gammav,
    const float* __restrict__ betav,
    const float* __restrict__ rmean,
    const float* __restrict__ rvar,
    float*       __restrict__ out,
    int N)
{
    const int lane = threadIdx.x & 63;
    const int wid  = threadIdx.x >> 6;
    const int d    = lane;

    // ---- per-lane channel constants (amortized over 4 pillars) ----
    const float w0 = W[0*64+d], w1 = W[1*64+d], w2 = W[2*64+d];
    const float w3 = W[3*64+d], w4 = W[4*64+d], w5 = W[5*64+d];
    const float w6 = W[6*64+d], w7 = W[7*64+d], w8 = W[8*64+d];
    const float inv   = gammav[d] * rsqrtf(rvar[d] + 1e-3f);
    const float shift = fmaf(-rmean[d], inv, betav[d]);
    const float A  = (w0 + w4 + w7) * inv;
    const float B  = (w1 + w5 + w8) * inv;
    const float C  = (w2 + w6) * inv;
    const float Dk = w3 * inv;
    const float P4 = w4*inv, P5 = w5*inv, P6 = w6*inv, P7 = w7*inv, P8 = w8*inv;

    const int base = blockIdx.x * 16 + wid * 4;   // 4 pillars per wave
    if (base >= N) return;

    // ---- per-pillar scalar meta (uniform indices -> s_load) ----
    const int s0 = min(base + 0, N - 1), s1 = min(base + 1, N - 1);
    const int s2 = min(base + 2, N - 1), s3 = min(base + 3, N - 1);
    const int np0 = num_points[s0], np1 = num_points[s1];
    const int np2 = num_points[s2], np3 = num_points[s3];
    const int cx0 = coords[s0*3], cy0 = coords[s0*3+1];
    const int cx1 = coords[s1*3], cy1 = coords[s1*3+1];
    const int cx2 = coords[s2*3], cy2 = coords[s2*3+1];
    const int cx3 = coords[s3*3], cy3 = coords[s3*3+1];

    // ---- point data: lane = point; 2 pillars per dwordx4 load ----
    const int pt = lane & 31;
    const int pilA = (lane >= 32) ? s1 : s0;
    const int pilB = (lane >= 32) ? s3 : s2;
    const float4 g0 = *(const float4*)(voxels + (size_t)pilA * 128 + pt * 4);
    const float4 g1 = *(const float4*)(voxels + (size_t)pilB * 128 + pt * 4);

    // ---- xyz sums over ALL 32 points (ref sums padding too), DPP 16-group ----
    const float bx0 = sum16(g0.x), by0 = sum16(g0.y), bz0 = sum16(g0.z);
    const float bx1 = sum16(g1.x), by1 = sum16(g1.y), bz1 = sum16(g1.z);

    auto pillarBody = [&](const float4& q, int LB, int sp, bool ok,
                          int np, int cxi, int cyi,
                          float sxlo, float sxhi, float sylo, float syhi,
                          float szlo, float szhi) {
        const float cxf = fmaf((float)cxi, 0.2f, 0.1f);    // VX/2 + 0
        const float cyf = fmaf((float)cyi, 0.2f, -25.5f);  // VY/2 - 25.6
        const float E2  = shift - cxf*P7 - cyf*P8;         // mean term deferred

        // point-0 data (always valid: np >= 1) for padded-slot substitution
        const int x0i = __builtin_amdgcn_readlane(__float_as_int(q.x), LB);
        const int y0i = __builtin_amdgcn_readlane(__float_as_int(q.y), LB);
        const int z0i = __builtin_amdgcn_readlane(__float_as_int(q.z), LB);
        const int w0i = __builtin_amdgcn_readlane(__float_as_int(q.w), LB);

        float m0 = -INFINITY, m1 = -INFINITY;
        POINT(q, LB, 0, m0); POINT(q, LB, 1, m1);
        POINT(q, LB, 2, m0); POINT(q, LB, 3, m1);
        POINT(q, LB, 4, m0); POINT(q, LB, 5, m1);
        POINT(q, LB, 6, m0); POINT(q, LB, 7, m1);
        if (np > 8) {
            POINT(q, LB,  8, m0); POINT(q, LB,  9, m1);
            POINT(q, LB, 10, m0); POINT(q, LB, 11, m1);
            POINT(q, LB, 12, m0); POINT(q, LB, 13, m1);
            POINT(q, LB, 14, m0); POINT(q, LB, 15, m1);
        }
        if (np > 16) {
            POINT(q, LB, 16, m0); POINT(q, LB, 17, m1);
            POINT(q, LB, 18, m0); POINT(q, LB, 19, m1);
            POINT(q, LB, 20, m0); POINT(q, LB, 21, m1);
            POINT(q, LB, 22, m0); POINT(q, LB, 23, m1);
        }
        if (np > 24) {
            POINT(q, LB, 24, m0); POINT(q, LB, 25, m1);
            POINT(q, LB, 26, m0); POINT(q, LB, 27, m1);
            POINT(q, LB, 28, m0); POINT(q, LB, 29, m1);
            POINT(q, LB, 30, m0); POINT(q, LB, 31, m1);
        }

        // deferred mean term from 16-group half sums (each FMA reads 1 SGPR)
        float S = sxlo * P4;
        S = fmaf(sxhi, P4, S);
        S = fmaf(sylo, P5, S); S = fmaf(syhi, P5, S);
        S = fmaf(szlo, P6, S); S = fmaf(szhi, P6, S);
        S *= __builtin_amdgcn_rcpf((float)np);

        float mf = fmaxf(m0, m1) - S;
        if (np < MAXP) mf = fmaxf(mf, shift);  // padded points contribute `shift`
        if (ok) out[(size_t)sp * 64 + d] = fmaxf(mf, 0.0f);
    };

    pillarBody(g0,  0, s0, base + 0 < N, np0, cx0, cy0,
               rdlanef(bx0,  0), rdlanef(bx0, 16),
               rdlanef(by0,  0), rdlanef(by0, 16),
               rdlanef(bz0,  0), rdlanef(bz0, 16));
    pillarBody(g0, 32, s1, base + 1 < N, np1, cx1, cy1,
               rdlanef(bx0, 32), rdlanef(bx0, 48),
               rdlanef(by0, 32), rdlanef(by0, 48),
               rdlanef(bz0, 32), rdlanef(bz0, 48));
    pillarBody(g1,  0, s2, base + 2 < N, np2, cx2, cy2,
               rdlanef(bx1,  0), rdlanef(bx1, 16),
               rdlanef(by1,  0), rdlanef(by1, 16),
               rdlanef(bz1,  0), rdlanef(bz1, 16));
    pillarBody(g1, 32, s3, base + 3 < N, np3, cx3, cy3,
               rdlanef(bx1, 32), rdlanef(bx1, 48),
               rdlanef(by1, 32), rdlanef(by1, 48),
               rdlanef(bz1, 32), rdlanef(bz1, 48));
}

extern "C" void kernel_launch(void* const* d_in, const int* in_sizes, int n_in,
                              void* d_out, int out_size, void* d_ws, size_t ws_size,
                              hipStream_t stream) {
    const float* voxels     = (const float*)d_in[0];
    const int*   num_points = (const int*)  d_in[1];
    const int*   coords     = (const int*)  d_in[2];
    const float* W          = (const float*)d_in[3];
    const float* gammav     = (const float*)d_in[4];
    const float* betav      = (const float*)d_in[5];
    const float* rmean      = (const float*)d_in[6];
    const float* rvar       = (const float*)d_in[7];
    float*       out        = (float*)d_out;

    const int N = in_sizes[1];                 // one entry per pillar
    const int blocks = (N + 15) / 16;          // 16 pillars per 256-thr block
    pfn_kernel<<<blocks, 256, 0, stream>>>(voxels, num_points, coords, W,
                                           gammav, betav, rmean, rvar, out, N);
}

// Round 9
// 34.236 us; speedup vs baseline: 2.3606x; 2.3606x over previous
//
#include <hip/hip_runtime.h>
#include <hip/hip_bf16.h>
#include <math.h>

#define MAXP 32
#define PPW  8   // pillars per wave

typedef __attribute__((ext_vector_type(8)))  short bf16x8;
typedef __attribute__((ext_vector_type(16))) float f32x16;

template <int CTRL>
__device__ __forceinline__ float dppadd(float v) {
    int t = __builtin_amdgcn_update_dpp(0, __float_as_int(v), CTRL, 0xF, 0xF, false);
    return v + __int_as_float(t);
}
// sum within each 16-lane group (HW-verified in R6/R7)
__device__ __forceinline__ float sum16(float v) {
    v = dppadd<0xB1>(v);    // xor1
    v = dppadd<0x4E>(v);    // xor2
    v = dppadd<0x141>(v);   // row_half_mirror
    v = dppadd<0x140>(v);   // row_mirror
    return v;
}
__device__ __forceinline__ float rdf(float v, int l) {
    return __int_as_float(__builtin_amdgcn_readlane(__float_as_int(v), l));
}
__device__ __forceinline__ int pkbf(float a, float b) {   // pack 2 bf16 (RN)
    __hip_bfloat16 ha = __float2bfloat16(a), hb = __float2bfloat16(b);
    unsigned short ua = *reinterpret_cast<unsigned short*>(&ha);
    unsigned short ub = *reinterpret_cast<unsigned short*>(&hb);
    return (int)ua | ((int)ub << 16);
}
__device__ __forceinline__ float rmax16(f32x16 a) {       // max3-friendly tree
    float m1 = fmaxf(fmaxf(a[0], a[1]),  a[2]);
    float m2 = fmaxf(fmaxf(a[3], a[4]),  a[5]);
    float m3 = fmaxf(fmaxf(a[6], a[7]),  a[8]);
    float m4 = fmaxf(fmaxf(a[9], a[10]), a[11]);
    float m5 = fmaxf(fmaxf(a[12],a[13]), a[14]);
    float mm = fmaxf(fmaxf(m1, m2), m3);
    return fmaxf(fmaxf(fmaxf(m4, m5), a[15]), mm);
}

union FragAB { bf16x8 v; int i[4]; };

__global__ __launch_bounds__(256) void pfn_kernel(
    const float* __restrict__ voxels,
    const int*   __restrict__ num_points,
    const int*   __restrict__ coords,
    const float* __restrict__ W,
    const float* __restrict__ gammav,
    const float* __restrict__ betav,
    const float* __restrict__ rmean,
    const float* __restrict__ rvar,
    float*       __restrict__ out,
    int N)
{
    const int lane = threadIdx.x & 63;
    const int wid  = threadIdx.x >> 6;
    const int pt   = lane & 31;           // point slot (A-frag row)
    const int cL   = lane & 31;           // channel for MFMA-lo (B col)
    const int cH   = cL + 32;             // channel for MFMA-hi

    const int base = (blockIdx.x * 4 + wid) * PPW;
    if (base >= N) return;

    // ---- per-wave setup: folded coefficients for both channel halves ----
    float AL,BL,CLc,DLc,P4L,P5L,P6L,P7L,P8L,shL;
    float AH,BH,CHc,DHc,P4H,P5H,P6H,P7H,P8H,shH;
    {
        float w0=W[0*64+cL],w1=W[64+cL],w2=W[128+cL],w3=W[192+cL],w4=W[256+cL],
              w5=W[320+cL],w6=W[384+cL],w7=W[448+cL],w8=W[512+cL];
        float inv = gammav[cL] * rsqrtf(rvar[cL] + 1e-3f);
        shL = fmaf(-rmean[cL], inv, betav[cL]);
        AL=(w0+w4+w7)*inv; BL=(w1+w5+w8)*inv; CLc=(w2+w6)*inv; DLc=w3*inv;
        P4L=w4*inv; P5L=w5*inv; P6L=w6*inv; P7L=w7*inv; P8L=w8*inv;
    }
    {
        float w0=W[0*64+cH],w1=W[64+cH],w2=W[128+cH],w3=W[192+cH],w4=W[256+cH],
              w5=W[320+cH],w6=W[384+cH],w7=W[448+cH],w8=W[512+cH];
        float inv = gammav[cH] * rsqrtf(rvar[cH] + 1e-3f);
        shH = fmaf(-rmean[cH], inv, betav[cH]);
        AH=(w0+w4+w7)*inv; BH=(w1+w5+w8)*inv; CHc=(w2+w6)*inv; DHc=w3*inv;
        P4H=w4*inv; P5H=w5*inv; P6H=w6*inv; P7H=w7*inv; P8H=w8*inv;
    }
    // B-frags: lane<32 holds B[k=0..7][col]; k=0..3 = (A,B,C,Dk), k>=4 zero.
    // lanes>=32 hold B[k=8..15][col] = 0.  (A-frag k>=4 values are then don't-care.)
    FragAB fbL, fbH;
    fbL.i[0] = pkbf(AL, BL); fbL.i[1] = pkbf(CLc, DLc); fbL.i[2] = 0; fbL.i[3] = 0;
    fbH.i[0] = pkbf(AH, BH); fbH.i[1] = pkbf(CHc, DHc); fbH.i[2] = 0; fbH.i[3] = 0;
    if (lane >= 32) { fbL.i[0] = fbL.i[1] = 0; fbH.i[0] = fbH.i[1] = 0; }

    const f32x16 zacc = {0,0,0,0,0,0,0,0,0,0,0,0,0,0,0,0};

    // ---- prologue: loads for first pillar (rotation prefetch) ----
    int sp = min(base, N - 1);
    float4 g = *(const float4*)(voxels + (size_t)sp * 128 + pt * 4); // lane=point
    int np = num_points[sp];
    int c0 = coords[sp * 3 + 0];
    int c1 = coords[sp * 3 + 1];

    #pragma unroll 1
    for (int i = 0; i < PPW; ++i) {
        const int    pc  = base + i;
        const float4 gc  = g;
        const int    npu = __builtin_amdgcn_readfirstlane(np);
        const int    c0c = c0, c1c = c1;

        // prefetch next pillar (VMEM/SMEM fly under this pillar's compute)
        if (i + 1 < PPW) {
            sp = min(base + i + 1, N - 1);
            g  = *(const float4*)(voxels + (size_t)sp * 128 + pt * 4);
            np = num_points[sp];
            c0 = coords[sp * 3 + 0];
            c1 = coords[sp * 3 + 1];
        }

        // ---- xyz sums over ALL 32 slots (ref's mean includes padding) ----
        const float bx = sum16(gc.x), by = sum16(gc.y), bz = sum16(gc.z);
        const float sxv = rdf(bx, 0) + rdf(bx, 16);
        const float syv = rdf(by, 0) + rdf(by, 16);
        const float szv = rdf(bz, 0) + rdf(bz, 16);

        // ---- A-frag staging: padded rows duplicate point 0 (max unchanged) ----
        const bool cv = (pt < npu);
        const float xs = cv ? gc.x : rdf(gc.x, 0);
        const float ys = cv ? gc.y : rdf(gc.y, 0);
        const float zs = cv ? gc.z : rdf(gc.z, 0);
        const float ws = cv ? gc.w : rdf(gc.w, 0);
        FragAB fa;
        fa.i[0] = pkbf(xs, ys); fa.i[1] = pkbf(zs, ws); fa.i[2] = 0; fa.i[3] = 0;

        // ---- 2 MFMAs: [32 pts x 4 feat] x [4 x 32 ch] per channel half ----
        f32x16 accL = __builtin_amdgcn_mfma_f32_32x32x16_bf16(fa.v, fbL.v, zacc, 0, 0, 0);
        f32x16 accH = __builtin_amdgcn_mfma_f32_32x32x16_bf16(fa.v, fbH.v, zacc, 0, 0, 0);

        // ---- max over points: 16 regs per lane + cross-half merge ----
        float mL = rmax16(accL);
        float mH = rmax16(accH);
        mL = fmaxf(mL, __shfl_xor(mL, 32));
        mH = fmaxf(mH, __shfl_xor(mH, 32));

        // ---- deferred mean + center terms, shift, relu ----
        const float rnp = __builtin_amdgcn_rcpf((float)npu);
        const float SL  = fmaf(sxv, P4L, fmaf(syv, P5L, szv * P6L)) * rnp;
        const float SH  = fmaf(sxv, P4H, fmaf(syv, P5H, szv * P6H)) * rnp;
        const float cxf = fmaf((float)c0c, 0.2f, 0.1f);    // VX/2 + 0
        const float cyf = fmaf((float)c1c, 0.2f, -25.5f);  // VY/2 - 25.6
        float vL = mL + (shL - cxf * P7L - cyf * P8L) - SL;
        float vH = mH + (shH - cxf * P7H - cyf * P8H) - SH;
        if (npu < MAXP) { vL = fmaxf(vL, shL); vH = fmaxf(vH, shH); }
        vL = fmaxf(vL, 0.0f);
        vH = fmaxf(vH, 0.0f);

        // lane<32 stores ch=lane (lo); lane>=32 stores ch=lane (hi): one
        // contiguous 256B dword store per pillar.
        const float o = (lane < 32) ? vL : vH;
        if (pc < N) out[(size_t)pc * 64 + lane] = o;
    }
}

extern "C" void kernel_launch(void* const* d_in, const int* in_sizes, int n_in,
                              void* d_out, int out_size, void* d_ws, size_t ws_size,
                              hipStream_t stream) {
    const float* voxels     = (const float*)d_in[0];
    const int*   num_points = (const int*)  d_in[1];
    const int*   coords     = (const int*)  d_in[2];
    const float* W          = (const float*)d_in[3];
    const float* gammav     = (const float*)d_in[4];
    const float* betav      = (const float*)d_in[5];
    const float* rmean      = (const float*)d_in[6];
    const float* rvar       = (const float*)d_in[7];
    float*       out        = (float*)d_out;

    const int N = in_sizes[1];                    // one entry per pillar
    const int per_block = 4 * PPW;                // 4 waves x PPW pillars
    const int blocks = (N + per_block - 1) / per_block;
    pfn_kernel<<<blocks, 256, 0, stream>>>(voxels, num_points, coords, W,
                                           gammav, betav, rmean, rvar, out, N);
}

// Round 10
// 31.847 us; speedup vs baseline: 2.5377x; 1.0750x over previous
//
#include <hip/hip_runtime.h>
#include <hip/hip_bf16.h>
#include <math.h>

#define MAXP 32
#define PPW  8   // pillars per wave

typedef __attribute__((ext_vector_type(8)))  short bf16x8;
typedef __attribute__((ext_vector_type(16))) float f32x16;

template <int CTRL>
__device__ __forceinline__ float dppadd(float v) {
    int t = __builtin_amdgcn_update_dpp(0, __float_as_int(v), CTRL, 0xF, 0xF, false);
    return v + __int_as_float(t);
}
// sum within each 16-lane group (HW-verified R6-R9)
__device__ __forceinline__ float sum16(float v) {
    v = dppadd<0xB1>(v);    // xor1
    v = dppadd<0x4E>(v);    // xor2
    v = dppadd<0x141>(v);   // row_half_mirror
    v = dppadd<0x140>(v);   // row_mirror
    return v;
}
__device__ __forceinline__ float rdf(float v, int l) {
    return __int_as_float(__builtin_amdgcn_readlane(__float_as_int(v), l));
}
// 1-instruction bf16 pair pack (lo -> low16, hi -> high16)
__device__ __forceinline__ int cvtpk(float lo, float hi) {
    int r;
    asm("v_cvt_pk_bf16_f32 %0, %1, %2" : "=v"(r) : "v"(lo), "v"(hi));
    return r;
}
__device__ __forceinline__ float rmax16(f32x16 a) {       // max3-fused tree
    float m1 = fmaxf(fmaxf(a[0], a[1]),  a[2]);
    float m2 = fmaxf(fmaxf(a[3], a[4]),  a[5]);
    float m3 = fmaxf(fmaxf(a[6], a[7]),  a[8]);
    float m4 = fmaxf(fmaxf(a[9], a[10]), a[11]);
    float m5 = fmaxf(fmaxf(a[12],a[13]), a[14]);
    float mm = fmaxf(fmaxf(m1, m2), m3);
    return fmaxf(fmaxf(fmaxf(m4, m5), a[15]), mm);
}

union FragAB { bf16x8 v; int i[4]; };

__global__ __launch_bounds__(256) void pfn_kernel(
    const float* __restrict__ voxels,
    const int*   __restrict__ num_points,
    const int*   __restrict__ coords,
    const float* __restrict__ W,
    const float* __restrict__ gammav,
    const float* __restrict__ betav,
    const float* __restrict__ rmean,
    const float* __restrict__ rvar,
    float*       __restrict__ out,
    int N)
{
    const int  lane = threadIdx.x & 63;
    const int  wid  = threadIdx.x >> 6;
    const int  pt   = lane & 31;          // A-frag row (point slot)
    const bool lo32 = (lane < 32);

    int vz;                               // opaque 0: pins small loads to VMEM
    asm("v_mov_b32 %0, 0" : "=v"(vz));

    const int base = (blockIdx.x * 4 + wid) * PPW;
    if (base >= N) return;

    // ---- per-lane channel coefficients for both halves (once per wave) ----
    const int cL = lane & 31, cH = cL + 32;
    float AL,BL,CLc,DLc,P4L,P5L,P6L,P7L,P8L,shL;
    float AH,BH,CHc,DHc,P4H,P5H,P6H,P7H,P8H,shH;
    {
        float w0=W[cL],w1=W[64+cL],w2=W[128+cL],w3=W[192+cL],w4=W[256+cL],
              w5=W[320+cL],w6=W[384+cL],w7=W[448+cL],w8=W[512+cL];
        float inv = gammav[cL] * rsqrtf(rvar[cL] + 1e-3f);
        shL = fmaf(-rmean[cL], inv, betav[cL]);
        AL=(w0+w4+w7)*inv; BL=(w1+w5+w8)*inv; CLc=(w2+w6)*inv; DLc=w3*inv;
        P4L=w4*inv; P5L=w5*inv; P6L=w6*inv; P7L=w7*inv; P8L=w8*inv;
    }
    {
        float w0=W[cH],w1=W[64+cH],w2=W[128+cH],w3=W[192+cH],w4=W[256+cH],
              w5=W[320+cH],w6=W[384+cH],w7=W[448+cH],w8=W[512+cH];
        float inv = gammav[cH] * rsqrtf(rvar[cH] + 1e-3f);
        shH = fmaf(-rmean[cH], inv, betav[cH]);
        AH=(w0+w4+w7)*inv; BH=(w1+w5+w8)*inv; CHc=(w2+w6)*inv; DHc=w3*inv;
        P4H=w4*inv; P5H=w5*inv; P6H=w6*inv; P7H=w7*inv; P8H=w8*inv;
    }

    // ---- B-frags: K-rows carry ALL linear terms ----
    // lanes 0-31 hold k=0..7:  (A, B, C, Dk, P4, P5, P6, -P7)
    // lanes 32-63 hold k=8..15: (-P8, shift, 0, 0, 0, 0, 0, 0)
    FragAB fbL, fbH;
    if (lo32) {
        fbL.i[0]=cvtpk(AL,BL);   fbL.i[1]=cvtpk(CLc,DLc);
        fbL.i[2]=cvtpk(P4L,P5L); fbL.i[3]=cvtpk(P6L,-P7L);
        fbH.i[0]=cvtpk(AH,BH);   fbH.i[1]=cvtpk(CHc,DHc);
        fbH.i[2]=cvtpk(P4H,P5H); fbH.i[3]=cvtpk(P6H,-P7H);
    } else {
        fbL.i[0]=cvtpk(-P8L,shL); fbL.i[1]=0; fbL.i[2]=0; fbL.i[3]=0;
        fbH.i[0]=cvtpk(-P8H,shH); fbH.i[1]=0; fbH.i[2]=0; fbH.i[3]=0;
    }

    const f32x16 zacc = {0,0,0,0,0,0,0,0,0,0,0,0,0,0,0,0};

    // ---- prologue loads for first pillar (all VMEM, vmcnt-scheduled) ----
    int sp = min(base, N - 1);
    float4 g   = *(const float4*)((const char*)voxels +
                                  (size_t)sp * 512 + (size_t)pt * 16);
    int    npv = *(const int*)((const char*)num_points + (size_t)sp*4  + vz);
    int    c0v = *(const int*)((const char*)coords     + (size_t)sp*12 + vz);
    int    c1v = *(const int*)((const char*)coords     + (size_t)sp*12 + 4 + vz);

    #pragma unroll 1
    for (int i = 0; i < PPW; ++i) {
        const float4 gc = g;
        const int    np = npv, c0 = c0v, c1 = c1v;

        // prefetch next pillar (VMEM in flight under this pillar's compute)
        if (i + 1 < PPW) {
            sp  = min(base + i + 1, N - 1);
            g   = *(const float4*)((const char*)voxels +
                                   (size_t)sp * 512 + (size_t)pt * 16);
            npv = *(const int*)((const char*)num_points + (size_t)sp*4  + vz);
            c0v = *(const int*)((const char*)coords     + (size_t)sp*12 + vz);
            c1v = *(const int*)((const char*)coords     + (size_t)sp*12 + 4 + vz);
        }

        // ---- xyz sums over ALL 32 slots (ref's mean includes padding) ----
        float bx = sum16(gc.x), by = sum16(gc.y), bz = sum16(gc.z);
        bx += __shfl_xor(bx, 16);        // full sum, uniform across lanes
        by += __shfl_xor(by, 16);
        bz += __shfl_xor(bz, 16);
        const float rnp = __builtin_amdgcn_rcpf((float)np);
        const float msx = -bx * rnp, msy = -by * rnp, msz = -bz * rnp;
        const float cxf = fmaf((float)c0, 0.2f, 0.1f);    // VX/2 + 0
        const float cyf = fmaf((float)c1, 0.2f, -25.5f);  // VY/2 - 25.6

        // ---- A-frag: padded rows (pt>=np) duplicate point 0 (max unchanged) ----
        const bool cv = (pt < np);
        const float xs = cv ? gc.x : rdf(gc.x, 0);
        const float ys = cv ? gc.y : rdf(gc.y, 0);
        const float zs = cv ? gc.z : rdf(gc.z, 0);
        const float ws = cv ? gc.w : rdf(gc.w, 0);
        // lanes 0-31: k=0..7 = (x,y,z,w, -sx/np,-sy/np,-sz/np, cx)
        // lanes 32-63: k=8..15 = (cy, 1, 0,...)  -> pairs with (-P8, shift)
        FragAB fa;
        fa.i[0] = lo32 ? cvtpk(xs, ys)   : cvtpk(cyf, 1.0f);
        fa.i[1] = lo32 ? cvtpk(zs, ws)   : 0;
        fa.i[2] = lo32 ? cvtpk(msx, msy) : 0;
        fa.i[3] = lo32 ? cvtpk(msz, cxf) : 0;

        // ---- 2 MFMAs produce the COMPLETE pre-max values ----
        f32x16 accL = __builtin_amdgcn_mfma_f32_32x32x16_bf16(fa.v, fbL.v, zacc, 0, 0, 0);
        f32x16 accH = __builtin_amdgcn_mfma_f32_32x32x16_bf16(fa.v, fbH.v, zacc, 0, 0, 0);

        // ---- max over 32 points: 16 in-register + cross-half merge ----
        float mL = rmax16(accL);
        float mH = rmax16(accH);
        mL = fmaxf(mL, __shfl_xor(mL, 32));
        mH = fmaxf(mH, __shfl_xor(mH, 32));

        // padded points contribute exactly `shift` (only when np < 32)
        const bool pad = (np < MAXP);
        mL = pad ? fmaxf(mL, shL) : mL;
        mH = pad ? fmaxf(mH, shH) : mH;

        const float o = fmaxf(lo32 ? mL : mH, 0.0f);   // relu
        const int pc = base + i;
        if (pc < N) out[(size_t)pc * 64 + lane] = o;
    }
}

extern "C" void kernel_launch(void* const* d_in, const int* in_sizes, int n_in,
                              void* d_out, int out_size, void* d_ws, size_t ws_size,
                              hipStream_t stream) {
    const float* voxels     = (const float*)d_in[0];
    const int*   num_points = (const int*)  d_in[1];
    const int*   coords     = (const int*)  d_in[2];
    const float* W          = (const float*)d_in[3];
    const float* gammav     = (const float*)d_in[4];
    const float* betav      = (const float*)d_in[5];
    const float* rmean      = (const float*)d_in[6];
    const float* rvar       = (const float*)d_in[7];
    float*       out        = (float*)d_out;

    const int N = in_sizes[1];                    // one entry per pillar
    const int per_block = 4 * PPW;                // 4 waves x PPW pillars
    const int blocks = (N + per_block - 1) / per_block;
    pfn_kernel<<<blocks, 256, 0, stream>>>(voxels, num_points, coords, W,
                                           gammav, betav, rmean, rvar, out, N);
}